// Round 3
// baseline (1030.004 us; speedup 1.0000x reference)
//
#include <hip/hip_runtime.h>

// WaveNet block: B=16, C=256, T=4096, LAYERS=8, K=2 (causal, dilation 2^l).
// bf16 MFMA GEMM per layer (M=256, N=B*T, K=512), 128x128 tile, BK=64,
// global_load_lds(16B) staging, XOR-swizzled LDS.
// Zout handling tiered by ws_size:
//   Tier B: 9-buffer bf16 Zs chain, final fp32 sum+transpose (no per-layer Zout)
//   Tier A: fp32 Zacc in [b][t][c] (coalesced rmw), final transpose
//   Tier D: legacy fp32 rmw into Zout [b][c][t] (smallest ws)

typedef __attribute__((ext_vector_type(8))) short s16x8;
typedef __attribute__((ext_vector_type(4))) short s16x4;
typedef __attribute__((ext_vector_type(4))) float f32x4;

#define NB 16
#define NC 256
#define NT 4096
#define TPAD 4224   // 128 (zero pad) + 4096
#define PADT 128
#define NLAYERS 8
#define KTOT 512    // C * Ktap

__device__ __forceinline__ short f2bf(float x) {
  union { float f; unsigned u; } v; v.f = x;
  unsigned u = v.u;
  unsigned r = (u + 0x7fffu + ((u >> 16) & 1u)) >> 16;  // RNE
  return (short)r;
}
__device__ __forceinline__ float bf2f(short s) {
  union { float f; unsigned u; } v; v.u = ((unsigned)(unsigned short)s) << 16;
  return v.f;
}

__device__ __forceinline__ void async16(short* lp, const short* gp) {
  __builtin_amdgcn_global_load_lds(
      (const __attribute__((address_space(1))) unsigned int*)gp,
      (__attribute__((address_space(3))) unsigned int*)lp,
      16, 0, 0);
}

// ---------------- prep kernels ----------------

// zero the t<0 pad region of nbuf consecutive X buffers (ws is poisoned 0xAA)
__global__ void zero_pads(short* __restrict__ base, int nbuf, size_t strideSh) {
  int idx = blockIdx.x * 256 + threadIdx.x;    // over nbuf * NB*PADT*NC
  if (idx >= nbuf * NB * PADT * NC) return;
  int j = idx >> 19;                            // / (NB*PADT*NC = 524288)
  int rem = idx & 524287;
  int b = rem >> 15;                            // / (PADT*NC)
  int r2 = rem & 32767;
  base[(size_t)j * strideSh + (size_t)b * TPAD * NC + r2] = 0;
}

// ys [b][c][t] fp32  ->  X0 [b][128+t][c] bf16 (LDS-tiled transpose)
__global__ void transpose_cast(const float* __restrict__ ys, short* __restrict__ X0) {
  __shared__ float tile[64][65];
  const int b = blockIdx.z, c0 = blockIdx.y * 64, t0 = blockIdx.x * 64;
  const int tid = threadIdx.x;
#pragma unroll
  for (int i = 0; i < 16; ++i) {
    int c = (tid >> 6) + i * 4;
    int t = tid & 63;
    tile[c][t] = ys[((size_t)(b * NC + c0 + c)) * NT + t0 + t];
  }
  __syncthreads();
#pragma unroll
  for (int i = 0; i < 2; ++i) {
    int q = tid + i * 256;                      // 512 chunks of 8 bf16
    int t = q >> 3, cc = (q & 7) * 8;
    s16x8 v;
#pragma unroll
    for (int j = 0; j < 8; ++j) v[j] = f2bf(tile[cc + j][t]);
    *(s16x8*)&X0[((size_t)(b * TPAD + PADT + t0 + t)) * NC + c0 + cc] = v;
  }
}

// weights [l][co][ci][kw] fp32 -> [l][co][kw*256+ci] bf16, filter & gate
__global__ void convert_w(const float* __restrict__ fw, const float* __restrict__ gw,
                          short* __restrict__ Wf, short* __restrict__ Wg) {
  int idx = blockIdx.x * 256 + threadIdx.x;     // over 8*256*512 = 1048576
  if (idx >= NLAYERS * NC * KTOT) return;
  int k = idx & (KTOT - 1);
  int row = idx >> 9;                           // l*256+co
  int kw = k >> 8, ci = k & 255;
  int src = (row * NC + ci) * 2 + kw;
  Wf[idx] = f2bf(fw[src]);
  Wg[idx] = f2bf(gw[src]);
}

// ---------------- fused layer kernel ----------------
// grid (2, 32, 16): m-tile, t-tile, batch.  256 threads = 4 waves.
// zmode (Tier D only): 1 = Zout store, 2 = Zout rmw, 0 = none.
// Zacc (Tier A): fp32 [b][t][c] accumulator; accinit=1 on layer 0.
__global__ __launch_bounds__(256, 3)
void wavenet_layer(const short* __restrict__ Xin, short* __restrict__ Xout,
                   const short* __restrict__ Wf, const short* __restrict__ Wg,
                   const float* __restrict__ bia_f, const float* __restrict__ bia_g,
                   float* __restrict__ Zout, float* __restrict__ Zacc,
                   int d, int zmode, int writeX, int accinit) {
  __shared__ short lds[24576];                  // 48 KB
  short* Af = lds;                              // [128 m][64 k], chunk-swizzled
  short* Ag = lds + 8192;
  short* Bt = lds + 16384;                      // [128 n][64 k], chunk-swizzled

  const int tid = threadIdx.x;
  const int wave = tid >> 6, lane = tid & 63;
  const int quad = lane >> 4, l16 = lane & 15;
  const int m0 = blockIdx.x * 128, t0 = blockIdx.y * 128, b = blockIdx.z;
  const int wm = wave >> 1, wn = wave & 1;
  const int xm = l16 & 7;                       // read-side XOR mask (row&7)

  f32x4 accf[4][4] = {};
  f32x4 accg[4][4] = {};

  for (int kk = 0; kk < 8; ++kk) {              // K = 512, BK = 64
    const int k0 = kk * 64;
    const int kw = kk >> 2;
    const int ci0 = k0 & 255;
    const int tshift = (kw == 0) ? -d : 0;      // tap 0 reads x[t-d]
    __syncthreads();                            // prev compute done
#pragma unroll
    for (int i = 0; i < 4; ++i) {
      int q = (i * 4 + wave) * 64 + lane;       // physical chunk id 0..1023
      int r = q >> 3;
      int kc = ((q & 7) ^ (r & 7)) * 8;         // swizzled source chunk
      async16(Af + q * 8, Wf + (size_t)(m0 + r) * KTOT + k0 + kc);
      async16(Ag + q * 8, Wg + (size_t)(m0 + r) * KTOT + k0 + kc);
      async16(Bt + q * 8,
              Xin + ((size_t)(b * TPAD + PADT + t0 + r + tshift)) * NC + ci0 + kc);
    }
    __syncthreads();                            // drains vmcnt (async LDS loads)
#pragma unroll
    for (int ks = 0; ks < 2; ++ks) {
      const int xo = ((ks * 4 + quad) ^ xm) * 8;  // swizzled chunk offset
      s16x8 bfr[4];
#pragma unroll
      for (int ni = 0; ni < 4; ++ni)
        bfr[ni] = *(const s16x8*)&Bt[(wn * 64 + ni * 16 + l16) * 64 + xo];
#pragma unroll
      for (int mi = 0; mi < 4; ++mi) {
        s16x8 af = *(const s16x8*)&Af[(wm * 64 + mi * 16 + l16) * 64 + xo];
        s16x8 ag = *(const s16x8*)&Ag[(wm * 64 + mi * 16 + l16) * 64 + xo];
#pragma unroll
        for (int ni = 0; ni < 4; ++ni) {
          accf[mi][ni] = __builtin_amdgcn_mfma_f32_16x16x32_bf16(af, bfr[ni], accf[mi][ni], 0, 0, 0);
          accg[mi][ni] = __builtin_amdgcn_mfma_f32_16x16x32_bf16(ag, bfr[ni], accg[mi][ni], 0, 0, 0);
        }
      }
    }
  }
  __syncthreads();                              // all LDS reads done; reuse as ZT

  short* ZT = lds;                              // [128 t][128 c] bf16, rotated

#pragma unroll
  for (int mi = 0; mi < 4; ++mi) {
#pragma unroll
    for (int ni = 0; ni < 4; ++ni) {
      const int mbase = m0 + wm * 64 + mi * 16 + quad * 4;   // global channel
      const int tl = wn * 64 + ni * 16 + l16;                // tile-local time
      const int t = t0 + tl;                                 // global time
      short pk[4];
#pragma unroll
      for (int r = 0; r < 4; ++r) {
        float f = accf[mi][ni][r] + bia_f[mbase + r];
        float g = accg[mi][ni][r] + bia_g[mbase + r];
        float ef = __expf(2.f * f);
        float th = 1.f - 2.f / (ef + 1.f);      // tanh, no-overflow form
        float sg = 1.f / (1.f + __expf(-g));
        float z = th * sg;
        if (zmode) {
          size_t zo = ((size_t)(b * NC + mbase + r)) * NT + t;
          if (zmode == 1) Zout[zo] = z; else Zout[zo] += z;
        }
        pk[r] = f2bf(z);
      }
      if (writeX) {
        // rotate-swizzle: physical col = (c + t*8) & 127  (stays 4-aligned)
        int cloc = wm * 64 + mi * 16 + quad * 4;
        short* dst = &ZT[tl * 128 + ((cloc + tl * 8) & 127)];
        *(s16x4*)dst = (s16x4){pk[0], pk[1], pk[2], pk[3]};
      }
    }
  }
  if (writeX) {
    __syncthreads();
#pragma unroll
    for (int i = 0; i < 8; ++i) {
      int q = tid + i * 256;                    // 2048 chunks of 16B
      int t = q >> 4, cc = (q & 15) * 8;
      s16x8 v = *(const s16x8*)&ZT[t * 128 + ((cc + t * 8) & 127)];
      *(s16x8*)&Xout[((size_t)(b * TPAD + PADT + t0 + t)) * NC + m0 + cc] = v;
      if (Zacc) {
        // fp32 accumulator in [b][t][c]: fully-coalesced float4 rmw
        size_t zo = ((size_t)(b * NT + t0 + t)) * NC + m0 + cc;
        float4* zp = (float4*)&Zacc[zo];
        float4 a0, a1;
        if (accinit) { a0 = make_float4(0, 0, 0, 0); a1 = a0; }
        else { a0 = zp[0]; a1 = zp[1]; }
        a0.x += bf2f(v[0]); a0.y += bf2f(v[1]); a0.z += bf2f(v[2]); a0.w += bf2f(v[3]);
        a1.x += bf2f(v[4]); a1.y += bf2f(v[5]); a1.z += bf2f(v[6]); a1.w += bf2f(v[7]);
        zp[0] = a0; zp[1] = a1;
      }
    }
  }
}

// ---------------- Tier B final: sum 8 bf16 Zs buffers + transpose ----------------
__global__ void sum_transpose(const short* __restrict__ base, size_t strideSh,
                              float* __restrict__ Zout) {
  __shared__ float tile[64][65];
  const int b = blockIdx.z, c0 = blockIdx.y * 64, t0 = blockIdx.x * 64;
  const int tid = threadIdx.x;
  float acc[2][8] = {};
#pragma unroll
  for (int l = 1; l <= NLAYERS; ++l) {
    const short* buf = base + (size_t)l * strideSh;
#pragma unroll
    for (int j = 0; j < 2; ++j) {
      int chunk = tid + j * 256;                // 512 chunks of 8 bf16
      int tl = chunk >> 3, cc = (chunk & 7) * 8;
      s16x8 v = *(const s16x8*)&buf[((size_t)(b * TPAD + PADT + t0 + tl)) * NC + c0 + cc];
#pragma unroll
      for (int e = 0; e < 8; ++e) acc[j][e] += bf2f(v[e]);
    }
  }
#pragma unroll
  for (int j = 0; j < 2; ++j) {
    int chunk = tid + j * 256;
    int tl = chunk >> 3, cc = (chunk & 7) * 8;
#pragma unroll
    for (int e = 0; e < 8; ++e) tile[tl][cc + e] = acc[j][e];
  }
  __syncthreads();
#pragma unroll
  for (int i = 0; i < 4; ++i) {
    int c = (tid >> 4) + i * 16;
    int t = (tid & 15) * 4;
    float4 v = make_float4(tile[t][c], tile[t + 1][c], tile[t + 2][c], tile[t + 3][c]);
    *(float4*)&Zout[((size_t)(b * NC + c0 + c)) * NT + t0 + t] = v;
  }
}

// ---------------- Tier A final: transpose fp32 Zacc [b][t][c] -> Zout ----------------
__global__ void zacc_to_out(const float* __restrict__ Zacc, float* __restrict__ Zout) {
  __shared__ float tile[64][65];
  const int b = blockIdx.z, c0 = blockIdx.y * 64, t0 = blockIdx.x * 64;
  const int tid = threadIdx.x;
#pragma unroll
  for (int i = 0; i < 4; ++i) {
    int q = tid + i * 256;                      // 1024 chunks of 4 floats
    int tl = q >> 4, cc = (q & 15) * 4;
    float4 v = *(const float4*)&Zacc[((size_t)(b * NT + t0 + tl)) * NC + c0 + cc];
    tile[tl][cc] = v.x; tile[tl][cc + 1] = v.y;
    tile[tl][cc + 2] = v.z; tile[tl][cc + 3] = v.w;
  }
  __syncthreads();
#pragma unroll
  for (int i = 0; i < 4; ++i) {
    int c = (tid >> 4) + i * 16;
    int t = (tid & 15) * 4;
    float4 v = make_float4(tile[t][c], tile[t + 1][c], tile[t + 2][c], tile[t + 3][c]);
    *(float4*)&Zout[((size_t)(b * NC + c0 + c)) * NT + t0 + t] = v;
  }
}

// ---------------- launch ----------------
extern "C" void kernel_launch(void* const* d_in, const int* in_sizes, int n_in,
                              void* d_out, int out_size, void* d_ws, size_t ws_size,
                              hipStream_t stream) {
  const float* ys = (const float*)d_in[0];
  const float* fw = (const float*)d_in[1];
  const float* fb = (const float*)d_in[2];
  const float* gw = (const float*)d_in[3];
  const float* gb = (const float*)d_in[4];
  float* Zout = (float*)d_out;

  char* ws = (char*)d_ws;
  const size_t xbytes = (size_t)NB * TPAD * NC * 2;      // 34.6 MB each
  const size_t strideSh = xbytes / 2;
  const size_t wcount = (size_t)NLAYERS * NC * KTOT;     // per tensor
  const size_t wbytes = 2 * wcount * 2;                  // 4.2 MB
  const size_t zaccbytes = (size_t)NB * NT * NC * 4;     // 67.1 MB
  const size_t need_B = 9 * xbytes + wbytes;             // ~316 MB
  const size_t need_A = 2 * xbytes + zaccbytes + wbytes; // ~141 MB

  const int tier = (ws_size >= need_B) ? 2 : (ws_size >= need_A) ? 1 : 0;

  short* Xbase = (short*)ws;
  float* Zacc = nullptr;
  short* Wf;
  if (tier == 2) {
    Wf = (short*)(ws + 9 * xbytes);
  } else if (tier == 1) {
    Zacc = (float*)(ws + 2 * xbytes);
    Wf = (short*)(ws + 2 * xbytes + zaccbytes);
  } else {
    Wf = (short*)(ws + 2 * xbytes);
  }
  short* Wg = Wf + wcount;

  {
    int nbuf = (tier == 2) ? 8 : 2;
    int total = nbuf * NB * PADT * NC;
    hipLaunchKernelGGL(zero_pads, dim3((total + 255) / 256), dim3(256), 0, stream,
                       Xbase, nbuf, strideSh);
  }
  hipLaunchKernelGGL(transpose_cast, dim3(64, 4, 16), dim3(256), 0, stream, ys, Xbase);
  hipLaunchKernelGGL(convert_w, dim3(4096), dim3(256), 0, stream, fw, gw, Wf, Wg);

  for (int l = 0; l < NLAYERS; ++l) {
    const short* Xin;
    short* Xo;
    int zmode = 0, writeX = 1, accinit = 0;
    float* za = nullptr;
    if (tier == 2) {
      Xin = Xbase + (size_t)l * strideSh;
      Xo = Xbase + (size_t)(l + 1) * strideSh;
    } else if (tier == 1) {
      Xin = (l & 1) ? Xbase + strideSh : Xbase;
      Xo = (l & 1) ? Xbase : Xbase + strideSh;
      za = Zacc;
      accinit = (l == 0) ? 1 : 0;
    } else {
      Xin = (l & 1) ? Xbase + strideSh : Xbase;
      Xo = (l & 1) ? Xbase : Xbase + strideSh;
      zmode = (l == 0) ? 1 : 2;
      writeX = (l < NLAYERS - 1) ? 1 : 0;
    }
    hipLaunchKernelGGL(wavenet_layer, dim3(2, 32, 16), dim3(256), 0, stream,
                       Xin, Xo,
                       Wf + (size_t)l * NC * KTOT, Wg + (size_t)l * NC * KTOT,
                       fb + l * NC, gb + l * NC, Zout, za, 1 << l, zmode, writeX, accinit);
  }
  if (tier == 2) {
    hipLaunchKernelGGL(sum_transpose, dim3(64, 4, 16), dim3(256), 0, stream,
                       Xbase, strideSh, Zout);
  } else if (tier == 1) {
    hipLaunchKernelGGL(zacc_to_out, dim3(64, 4, 16), dim3(256), 0, stream, Zacc, Zout);
  }
}

// Round 4
// 770.680 us; speedup vs baseline: 1.3365x; 1.3365x over previous
//
#include <hip/hip_runtime.h>

// WaveNet block: B=16, C=256, T=4096, LAYERS=8, K=2 (causal, dilation 2^l).
// R4: barrier-free K-loop. A-fragments load direct global->VGPR from a
// pre-packed (MFMA-fragment-ordered) weight buffer; B-fragments load direct
// from Xin [b][t][c]. No LDS staging, no __syncthreads in the K-loop ->
// waves self-interleave loads and MFMA. LDS only for epilogue transpose.
// Zout deferred into fp16 Zacc [b][t][c] (coalesced rmw), final transpose.

typedef __attribute__((ext_vector_type(8))) short s16x8;
typedef __attribute__((ext_vector_type(4))) short s16x4;
typedef __attribute__((ext_vector_type(4))) float f32x4;
typedef __attribute__((ext_vector_type(8))) _Float16 h16x8;

#define NB 16
#define NC 256
#define NT 4096
#define TPAD 4224   // 128 (zero pad) + 4096
#define PADT 128
#define NLAYERS 8
#define KTOT 512    // C * Ktap

__device__ __forceinline__ short f2bf(float x) {
  union { float f; unsigned u; } v; v.f = x;
  unsigned u = v.u;
  unsigned r = (u + 0x7fffu + ((u >> 16) & 1u)) >> 16;  // RNE
  return (short)r;
}
__device__ __forceinline__ float bf2f(short s) {
  union { float f; unsigned u; } v; v.u = ((unsigned)(unsigned short)s) << 16;
  return v.f;
}

// ---------------- prep kernels ----------------

// zero the t<0 pad region of nbuf consecutive X buffers (ws is poisoned 0xAA)
__global__ void zero_pads(short* __restrict__ base, int nbuf, size_t strideSh) {
  int idx = blockIdx.x * 256 + threadIdx.x;
  if (idx >= nbuf * NB * PADT * NC) return;
  int j = idx >> 19;                            // / (NB*PADT*NC = 524288)
  int rem = idx & 524287;
  int b = rem >> 15;                            // / (PADT*NC)
  int r2 = rem & 32767;
  base[(size_t)j * strideSh + (size_t)b * TPAD * NC + r2] = 0;
}

// ys [b][c][t] fp32  ->  X0 [b][128+t][c] bf16 (LDS-tiled transpose)
__global__ void transpose_cast(const float* __restrict__ ys, short* __restrict__ X0) {
  __shared__ float tile[64][65];
  const int b = blockIdx.z, c0 = blockIdx.y * 64, t0 = blockIdx.x * 64;
  const int tid = threadIdx.x;
#pragma unroll
  for (int i = 0; i < 16; ++i) {
    int c = (tid >> 6) + i * 4;
    int t = tid & 63;
    tile[c][t] = ys[((size_t)(b * NC + c0 + c)) * NT + t0 + t];
  }
  __syncthreads();
#pragma unroll
  for (int i = 0; i < 2; ++i) {
    int q = tid + i * 256;                      // 512 chunks of 8 bf16
    int t = q >> 3, cc = (q & 7) * 8;
    s16x8 v;
#pragma unroll
    for (int j = 0; j < 8; ++j) v[j] = f2bf(tile[cc + j][t]);
    *(s16x8*)&X0[((size_t)(b * TPAD + PADT + t0 + t)) * NC + c0 + cc] = v;
  }
}

// weights [l][co][ci][kw] fp32 -> packed MFMA A-fragment order:
// idx = l*131072 + kk*16384 + ks*8192 + mb*2048 + mi*512 + lane*8 + j
// element = W[m = mb*64+mi*16+(lane&15)][k = kk*64+ks*32+(lane>>4)*8+j]
// (k -> kw = k>>8, ci = k&255). Each wave A-load = contiguous 1 KB.
__global__ void convert_w(const float* __restrict__ fw, const float* __restrict__ gw,
                          short* __restrict__ Wf, short* __restrict__ Wg) {
  int idx = blockIdx.x * 256 + threadIdx.x;     // over 8*256*512 = 1048576
  if (idx >= NLAYERS * NC * KTOT) return;
  int j    = idx & 7;
  int lane = (idx >> 3) & 63;
  int mi   = (idx >> 9) & 3;
  int mb   = (idx >> 11) & 3;
  int ks   = (idx >> 13) & 1;
  int kk   = (idx >> 14) & 7;
  int l    = idx >> 17;
  int m = mb * 64 + mi * 16 + (lane & 15);
  int k = kk * 64 + ks * 32 + (lane >> 4) * 8 + j;
  int kw = k >> 8, ci = k & 255;
  int src = ((l * NC + m) * NC + ci) * 2 + kw;
  Wf[idx] = f2bf(fw[src]);
  Wg[idx] = f2bf(gw[src]);
}

// ---------------- fused layer kernel ----------------
// grid (2, 32, 16): m-tile, t-tile, batch. 256 threads = 4 waves.
// Zacc: fp16 [b][t][c] accumulator (accinit=1 on layer 0).
// zmode (fallback only): 1 = Zout store, 2 = Zout rmw (fp32 [b][c][t]).
__global__ __launch_bounds__(256, 2)
void wavenet_layer(const short* __restrict__ Xin, short* __restrict__ Xout,
                   const short* __restrict__ Wf, const short* __restrict__ Wg,
                   const float* __restrict__ bia_f, const float* __restrict__ bia_g,
                   _Float16* __restrict__ Zacc, float* __restrict__ Zout,
                   int d, int accinit, int writeXout, int zmode) {
  __shared__ short ZT[128 * 128];               // 32 KB, epilogue only

  const int tid = threadIdx.x;
  const int wave = tid >> 6, lane = tid & 63;
  const int quad = lane >> 4, l16 = lane & 15;
  const int m0 = blockIdx.x * 128, t0 = blockIdx.y * 128, b = blockIdx.z;
  const int wm = wave >> 1, wn = wave & 1;

  f32x4 accf[4][4] = {};
  f32x4 accg[4][4] = {};

  // per-wave fragment base pointers (packed A; [t][c] B)
  const short* pAf = Wf + (blockIdx.x * 2 + wm) * 2048 + lane * 8;
  const short* pAg = Wg + (blockIdx.x * 2 + wm) * 2048 + lane * 8;
  const short* pB1 = Xin + ((size_t)(b * TPAD + PADT + t0 + wn * 64 + l16)) * NC + quad * 8;
  const short* pB0 = pB1 - (size_t)d * NC;      // tap 0 reads x[t-d]

  for (int kw = 0; kw < 2; ++kw) {              // 2 taps
    const short* pB = kw ? pB1 : pB0;
#pragma unroll
    for (int kc = 0; kc < 4; ++kc) {            // 4 ci-blocks of 64
      const int kk = kw * 4 + kc;
      s16x8 af[2][4], ag[2][4], bfr[2][4];
#pragma unroll
      for (int ks = 0; ks < 2; ++ks) {
#pragma unroll
        for (int mi = 0; mi < 4; ++mi) {
          af[ks][mi] = *(const s16x8*)(pAf + kk * 16384 + ks * 8192 + mi * 512);
          ag[ks][mi] = *(const s16x8*)(pAg + kk * 16384 + ks * 8192 + mi * 512);
        }
#pragma unroll
        for (int ni = 0; ni < 4; ++ni)
          bfr[ks][ni] = *(const s16x8*)(pB + (size_t)(ni * 16) * NC + kc * 64 + ks * 32);
      }
#pragma unroll
      for (int ks = 0; ks < 2; ++ks)
#pragma unroll
        for (int mi = 0; mi < 4; ++mi)
#pragma unroll
          for (int ni = 0; ni < 4; ++ni) {
            accf[mi][ni] = __builtin_amdgcn_mfma_f32_16x16x32_bf16(af[ks][mi], bfr[ks][ni], accf[mi][ni], 0, 0, 0);
            accg[mi][ni] = __builtin_amdgcn_mfma_f32_16x16x32_bf16(ag[ks][mi], bfr[ks][ni], accg[mi][ni], 0, 0, 0);
          }
    }
  }

  // -------- epilogue: bias + tanh*sigmoid, ZT transpose, Xout + Zacc --------
#pragma unroll
  for (int mi = 0; mi < 4; ++mi) {
#pragma unroll
    for (int ni = 0; ni < 4; ++ni) {
      const int mbase = m0 + wm * 64 + mi * 16 + quad * 4;   // global channel
      const int tl = wn * 64 + ni * 16 + l16;                // tile-local time
      const int t = t0 + tl;                                 // global time
      short pk[4];
#pragma unroll
      for (int r = 0; r < 4; ++r) {
        float f = accf[mi][ni][r] + bia_f[mbase + r];
        float g = accg[mi][ni][r] + bia_g[mbase + r];
        float ef = __expf(2.f * f);
        float th = 1.f - 2.f / (ef + 1.f);      // tanh, no-overflow form
        float sg = 1.f / (1.f + __expf(-g));
        float z = th * sg;
        if (zmode) {
          size_t zo = ((size_t)(b * NC + mbase + r)) * NT + t;
          if (zmode == 1) Zout[zo] = z; else Zout[zo] += z;
        }
        pk[r] = f2bf(z);
      }
      // rotate-swizzle: physical col = (c + t*8) & 127
      int cloc = wm * 64 + mi * 16 + quad * 4;
      short* dst = &ZT[tl * 128 + ((cloc + tl * 8) & 127)];
      *(s16x4*)dst = (s16x4){pk[0], pk[1], pk[2], pk[3]};
    }
  }
  __syncthreads();
#pragma unroll
  for (int i = 0; i < 8; ++i) {
    int q = tid + i * 256;                      // 2048 chunks of 16B
    int t = q >> 4, cc = (q & 15) * 8;
    s16x8 v = *(const s16x8*)&ZT[t * 128 + ((cc + t * 8) & 127)];
    if (writeXout)
      *(s16x8*)&Xout[((size_t)(b * TPAD + PADT + t0 + t)) * NC + m0 + cc] = v;
    if (Zacc) {
      size_t zo = ((size_t)(b * NT + t0 + t)) * NC + m0 + cc;
      h16x8* zp = (h16x8*)&Zacc[zo];
      h16x8 h;
      if (accinit) {
#pragma unroll
        for (int e = 0; e < 8; ++e) h[e] = (_Float16)bf2f(v[e]);
      } else {
        h = *zp;
#pragma unroll
        for (int e = 0; e < 8; ++e) h[e] = (_Float16)((float)h[e] + bf2f(v[e]));
      }
      *zp = h;
    }
  }
}

// ---------------- final: transpose fp16 Zacc [b][t][c] -> fp32 Zout [b][c][t] ----------------
__global__ void zacc_to_out(const _Float16* __restrict__ Zacc, float* __restrict__ Zout) {
  __shared__ float tile[64][65];
  const int b = blockIdx.z, c0 = blockIdx.y * 64, t0 = blockIdx.x * 64;
  const int tid = threadIdx.x;
#pragma unroll
  for (int i = 0; i < 2; ++i) {
    int q = tid + i * 256;                      // 512 chunks of 8 fp16
    int tl = q >> 3, cc = (q & 7) * 8;
    h16x8 v = *(const h16x8*)&Zacc[((size_t)(b * NT + t0 + tl)) * NC + c0 + cc];
#pragma unroll
    for (int e = 0; e < 8; ++e) tile[tl][cc + e] = (float)v[e];
  }
  __syncthreads();
#pragma unroll
  for (int i = 0; i < 4; ++i) {
    int c = (tid >> 4) + i * 16;
    int t = (tid & 15) * 4;
    float4 v = make_float4(tile[t][c], tile[t + 1][c], tile[t + 2][c], tile[t + 3][c]);
    *(float4*)&Zout[((size_t)(b * NC + c0 + c)) * NT + t0 + t] = v;
  }
}

// ---------------- launch ----------------
extern "C" void kernel_launch(void* const* d_in, const int* in_sizes, int n_in,
                              void* d_out, int out_size, void* d_ws, size_t ws_size,
                              hipStream_t stream) {
  const float* ys = (const float*)d_in[0];
  const float* fw = (const float*)d_in[1];
  const float* fb = (const float*)d_in[2];
  const float* gw = (const float*)d_in[3];
  const float* gb = (const float*)d_in[4];
  float* Zout = (float*)d_out;

  char* ws = (char*)d_ws;
  const size_t xbytes = (size_t)NB * TPAD * NC * 2;      // 34.6 MB each
  const size_t strideSh = xbytes / 2;
  const size_t wcount = (size_t)NLAYERS * NC * KTOT;     // per tensor
  const size_t wbytes = 2 * wcount * 2;                  // 4.2 MB
  const size_t zaccbytes = (size_t)NB * NT * NC * 2;     // 33.5 MB (fp16)
  const size_t need = 2 * xbytes + zaccbytes + wbytes;   // ~107 MB

  const bool defer = (ws_size >= need);

  short* Xbase = (short*)ws;
  _Float16* Zacc = nullptr;
  short* Wf;
  if (defer) {
    Zacc = (_Float16*)(ws + 2 * xbytes);
    Wf = (short*)(ws + 2 * xbytes + zaccbytes);
  } else {
    Wf = (short*)(ws + 2 * xbytes);
  }
  short* Wg = Wf + wcount;

  {
    int total = 2 * NB * PADT * NC;
    hipLaunchKernelGGL(zero_pads, dim3((total + 255) / 256), dim3(256), 0, stream,
                       Xbase, 2, strideSh);
  }
  hipLaunchKernelGGL(transpose_cast, dim3(64, 4, 16), dim3(256), 0, stream, ys, Xbase);
  hipLaunchKernelGGL(convert_w, dim3(4096), dim3(256), 0, stream, fw, gw, Wf, Wg);

  for (int l = 0; l < NLAYERS; ++l) {
    const short* Xin = (l & 1) ? Xbase + strideSh : Xbase;
    short* Xo = (l & 1) ? Xbase : Xbase + strideSh;
    int accinit = (l == 0) ? 1 : 0;
    int writeXout = (l < NLAYERS - 1) ? 1 : 0;
    int zmode = defer ? 0 : ((l == 0) ? 1 : 2);
    hipLaunchKernelGGL(wavenet_layer, dim3(2, 32, 16), dim3(256), 0, stream,
                       Xin, Xo,
                       Wf + (size_t)l * NC * KTOT, Wg + (size_t)l * NC * KTOT,
                       fb + l * NC, gb + l * NC, Zacc, Zout, 1 << l,
                       accinit, writeXout, zmode);
  }
  if (defer) {
    hipLaunchKernelGGL(zacc_to_out, dim3(64, 4, 16), dim3(256), 0, stream, Zacc, Zout);
  }
}